// Round 1
// baseline (1570.731 us; speedup 1.0000x reference)
//
#include <hip/hip_runtime.h>
#include <hip/hip_cooperative_groups.h>
#include <cmath>

namespace cg = cooperative_groups;

#define NBATCH 512
#define ND 512
#define NK 1024
#define NELEM (NBATCH * ND)          // 262144
#define NELEMF 262144.0f

// ws layout (float offsets)
#define ACC_OFF 0                    // 64 accumulator/scalar slots
#define BUF_OFF 64                   // 9 buffers of NELEM: Y,YN,FY,K2..K7
#define CT_OFF (64 + 9 * NELEM)      // transposed C: [1024][512]

#define RTOLc 1e-3f
#define ATOLc 1e-6f
#define TAc 1.0f
#define TBc 1.0f
#define TCc 0.0f

__device__ __forceinline__ float4 ld4(const float* p) { return *(const float4*)p; }
__device__ __forceinline__ void st4(float* p, float4 v) { *(float4*)p = v; }

// acc[c] += sum_{kk<512} sc[row][kk] * Bm[(k0+kk)*ND + col0 + c]
__device__ __forceinline__ void gemm_half(const float* __restrict__ Bm, int k0,
                                          const float (*sc)[520], int row, int col0,
                                          float4& acc) {
  const float* bp = Bm + (size_t)k0 * ND + col0;
#pragma unroll 4
  for (int kk = 0; kk < 512; kk += 4) {
    float4 sv = *(const float4*)(&sc[row][kk]);
    float4 b0 = ld4(bp + (size_t)(kk + 0) * ND);
    float4 b1 = ld4(bp + (size_t)(kk + 1) * ND);
    float4 b2 = ld4(bp + (size_t)(kk + 2) * ND);
    float4 b3 = ld4(bp + (size_t)(kk + 3) * ND);
    acc.x += sv.x * b0.x + sv.y * b1.x + sv.z * b2.x + sv.w * b3.x;
    acc.y += sv.x * b0.y + sv.y * b1.y + sv.z * b2.y + sv.w * b3.y;
    acc.z += sv.x * b0.z + sv.y * b1.z + sv.z * b2.z + sv.w * b3.z;
    acc.w += sv.x * b0.w + sv.y * b1.w + sv.z * b2.w + sv.w * b3.w;
  }
}

// out[b,n] = sum_k A[b,k]*Bm[k,n]   (512x512x512)
// mode 0: plain (also zeroes ACC slots).  mode 1: A selected from ws via ACC[32].
__global__ __launch_bounds__(256) void gemm_k512(const float* __restrict__ A,
                                                 const float* __restrict__ Bm,
                                                 float* __restrict__ out,
                                                 float* __restrict__ ws, int mode) {
  __shared__ float sc[16][520];
  if (mode == 0 && blockIdx.x == 0 && threadIdx.x < 64) ws[ACC_OFF + threadIdx.x] = 0.0f;
  const float* Ause = A;
  if (mode == 1) {
    float sel = ws[ACC_OFF + 32];
    Ause = ws + BUF_OFF + (sel > 0.5f ? NELEM : 0);
  }
  int row0 = (blockIdx.x >> 3) * 16;
  int colb = (blockIdx.x & 7) * 64;
  for (int idx = threadIdx.x; idx < 16 * 512; idx += 256) {
    int r = idx >> 9, kk = idx & 511;
    sc[r][kk] = Ause[(size_t)(row0 + r) * ND + kk];
  }
  __syncthreads();
  int row = threadIdx.x >> 4;
  int col0 = colb + (threadIdx.x & 15) * 4;
  float4 acc = {0.f, 0.f, 0.f, 0.f};
  gemm_half(Bm, 0, sc, row, col0, acc);
  st4(out + (size_t)(row0 + row) * ND + col0, acc);
}

// Ct[K][i] = C[i][K]   (C viewed as [512][1024], flat j*2+k == K)
__global__ __launch_bounds__(256) void transpose_c(const float* __restrict__ C,
                                                   float* __restrict__ Ct) {
  __shared__ float tile[32][33];
  int ib = blockIdx.x & 15;   // i-tile (512/32)
  int kb = blockIdx.x >> 4;   // K-tile (1024/32)
  for (int idx = threadIdx.x; idx < 1024; idx += 256) {
    int r = idx >> 5, c = idx & 31;
    tile[r][c] = C[(size_t)(ib * 32 + r) * NK + kb * 32 + c];
  }
  __syncthreads();
  for (int idx = threadIdx.x; idx < 1024; idx += 256) {
    int r = idx >> 5, c = idx & 31;
    Ct[(size_t)(kb * 32 + r) * ND + ib * 32 + c] = tile[c][r];
  }
}

__global__ __launch_bounds__(256) void ode_kernel(float* __restrict__ ws) {
  cg::grid_group grid = cg::this_grid();
  __shared__ float sc[16][520];
  __shared__ float red[4];
  __shared__ float shb;

  float* ACCp = ws + ACC_OFF;
  float* base = ws + BUF_OFF;
  float* bufY = base;
  float* bufYN = base + NELEM;
  float* bufFY = base + 2 * NELEM;
  float* K2b = base + 3 * NELEM;
  float* K3b = base + 4 * NELEM;
  float* K4b = base + 5 * NELEM;
  float* K5b = base + 6 * NELEM;
  float* K6b = base + 7 * NELEM;
  float* K7b = base + 8 * NELEM;
  const float* Ct = ws + CT_OFF;

  const int row0 = (blockIdx.x >> 3) * 16;
  const int colb = (blockIdx.x & 7) * 64;
  const int row = threadIdx.x >> 4;
  const int col0 = colb + (threadIdx.x & 15) * 4;
  const size_t gout = (size_t)(row0 + row) * ND + col0;

  float* Y = bufY;
  float* YN = bufYN;
  float* FY = bufFY;
  float* K7p = K7b;

  // stage: fill LDS with sin/cos(TA*(ybase + hs*sum cf*kb) + targ), GEMM vs Ct
  auto run_stage = [&](const float* ybase, int nc, const float* const* kb,
                       const float* cf, float hs, float targ, float* outbuf) -> float4 {
    float4 acc = {0.f, 0.f, 0.f, 0.f};
    for (int half = 0; half < 2; ++half) {
      __syncthreads();
      for (int idx = threadIdx.x; idx < 4096; idx += 256) {
        int r = idx >> 8, jj = idx & 255;
        int j = (half << 8) + jj;
        size_t g = (size_t)(row0 + r) * ND + j;
        float yv = ybase[g];
        float dv = 0.f;
        for (int m = 0; m < nc; ++m) dv += cf[m] * kb[m][g];
        yv += hs * dv;
        float s, c;
        __sincosf(TAc * yv + targ, &s, &c);
        sc[r][2 * jj] = s;
        sc[r][2 * jj + 1] = c;
      }
      __syncthreads();
      gemm_half(Ct, half * 512, sc, row, col0, acc);
    }
    if (outbuf) st4(outbuf + gout, acc);
    return acc;
  };

  auto block_atomic_sum = [&](float v, float* dst) {
    for (int o = 32; o; o >>= 1) v += __shfl_down(v, o, 64);
    __syncthreads();
    if ((threadIdx.x & 63) == 0) red[threadIdx.x >> 6] = v;
    __syncthreads();
    if (threadIdx.x == 0) atomicAdd(dst, red[0] + red[1] + red[2] + red[3]);
  };

  auto read_acc = [&](int slot) -> float {
    __syncthreads();
    if (threadIdx.x == 0) shb = atomicAdd(&ACCp[slot], 0.0f);
    __syncthreads();
    return shb;
  };

  // ---- initial step-size selection (scipy _select_initial_step) ----
  float4 f0 = run_stage(Y, 0, nullptr, nullptr, 0.f, TBc * 0.f + TCc, FY);
  float4 y0v = ld4(Y + gout);
  {
    float s0 = 0.f, s1 = 0.f;
    float sv;
    sv = ATOLc + RTOLc * fabsf(y0v.x); s0 += (y0v.x / sv) * (y0v.x / sv); s1 += (f0.x / sv) * (f0.x / sv);
    sv = ATOLc + RTOLc * fabsf(y0v.y); s0 += (y0v.y / sv) * (y0v.y / sv); s1 += (f0.y / sv) * (f0.y / sv);
    sv = ATOLc + RTOLc * fabsf(y0v.z); s0 += (y0v.z / sv) * (y0v.z / sv); s1 += (f0.z / sv) * (f0.z / sv);
    sv = ATOLc + RTOLc * fabsf(y0v.w); s0 += (y0v.w / sv) * (y0v.w / sv); s1 += (f0.w / sv) * (f0.w / sv);
    block_atomic_sum(s0, &ACCp[0]);
    block_atomic_sum(s1, &ACCp[1]);
  }
  grid.sync();
  float d0 = sqrtf(read_acc(0) / NELEMF);
  float d1 = sqrtf(read_acc(1) / NELEMF);
  float h0 = (d0 < 1e-5f || d1 < 1e-5f) ? 1e-6f : 0.01f * d0 / d1;

  const float onec = 1.0f;
  const float* kb1[1] = {FY};
  float4 f1 = run_stage(Y, 1, kb1, &onec, h0, TBc * h0 + TCc, nullptr);
  {
    float s2 = 0.f, sv, dfc;
    sv = ATOLc + RTOLc * fabsf(y0v.x); dfc = (f1.x - f0.x) / sv; s2 += dfc * dfc;
    sv = ATOLc + RTOLc * fabsf(y0v.y); dfc = (f1.y - f0.y) / sv; s2 += dfc * dfc;
    sv = ATOLc + RTOLc * fabsf(y0v.z); dfc = (f1.z - f0.z) / sv; s2 += dfc * dfc;
    sv = ATOLc + RTOLc * fabsf(y0v.w); dfc = (f1.w - f0.w) / sv; s2 += dfc * dfc;
    block_atomic_sum(s2, &ACCp[2]);
  }
  grid.sync();
  float d2 = sqrtf(read_acc(2) / NELEMF) / h0;
  float dmax = fmaxf(d1, d2);
  float h1 = (dmax <= 1e-15f) ? fmaxf(1e-6f, h0 * 1e-3f) : powf(0.01f / dmax, 0.2f);
  float h = fminf(fminf(100.f * h0, h1), 1.0f);
  float t = 0.f;
  bool done = false;

  // Dormand-Prince coefficients
  const float a21 = (float)(1.0 / 5.0);
  const float a31 = (float)(3.0 / 40.0), a32 = (float)(9.0 / 40.0);
  const float a41 = (float)(44.0 / 45.0), a42 = (float)(-56.0 / 15.0), a43 = (float)(32.0 / 9.0);
  const float a51 = (float)(19372.0 / 6561.0), a52 = (float)(-25360.0 / 2187.0),
              a53 = (float)(64448.0 / 6561.0), a54 = (float)(-212.0 / 729.0);
  const float a61 = (float)(9017.0 / 3168.0), a62 = (float)(-355.0 / 33.0),
              a63 = (float)(46732.0 / 5247.0), a64 = (float)(49.0 / 176.0),
              a65 = (float)(-5103.0 / 18656.0);
  const float b1 = (float)(35.0 / 384.0), b3 = (float)(500.0 / 1113.0), b4 = (float)(125.0 / 192.0),
              b5 = (float)(-2187.0 / 6784.0), b6 = (float)(11.0 / 84.0);
  const float e1 = (float)(71.0 / 57600.0), e3 = (float)(-71.0 / 16695.0), e4 = (float)(71.0 / 1920.0),
              e5 = (float)(-17253.0 / 339200.0), e6 = (float)(22.0 / 525.0), e7 = (float)(-1.0 / 40.0);

  const float* kbl[5];
  float cfl[5];
  int it = 0;
  while (!done && it < 20) {
    float hs = fminf(h, 1.0f - t);

    kbl[0] = FY; cfl[0] = a21;
    run_stage(Y, 1, kbl, cfl, hs, TBc * (t + 0.2f * hs) + TCc, K2b);
    grid.sync();

    kbl[0] = FY; kbl[1] = K2b; cfl[0] = a31; cfl[1] = a32;
    run_stage(Y, 2, kbl, cfl, hs, TBc * (t + 0.3f * hs) + TCc, K3b);
    grid.sync();

    kbl[0] = FY; kbl[1] = K2b; kbl[2] = K3b; cfl[0] = a41; cfl[1] = a42; cfl[2] = a43;
    run_stage(Y, 3, kbl, cfl, hs, TBc * (t + 0.8f * hs) + TCc, K4b);
    grid.sync();

    kbl[0] = FY; kbl[1] = K2b; kbl[2] = K3b; kbl[3] = K4b;
    cfl[0] = a51; cfl[1] = a52; cfl[2] = a53; cfl[3] = a54;
    run_stage(Y, 4, kbl, cfl, hs, TBc * (t + (float)(8.0 / 9.0) * hs) + TCc, K5b);
    grid.sync();

    kbl[0] = FY; kbl[1] = K2b; kbl[2] = K3b; kbl[3] = K4b; kbl[4] = K5b;
    cfl[0] = a61; cfl[1] = a62; cfl[2] = a63; cfl[3] = a64; cfl[4] = a65;
    float4 k6v = run_stage(Y, 5, kbl, cfl, hs, TBc * (t + hs) + TCc, K6b);

    // y_new tile (k2 has zero weight)
    float4 k1v = ld4(FY + gout);
    float4 k3v = ld4(K3b + gout);
    float4 k4v = ld4(K4b + gout);
    float4 k5v = ld4(K5b + gout);
    float4 yv = ld4(Y + gout);
    float4 ynv;
    ynv.x = yv.x + hs * (b1 * k1v.x + b3 * k3v.x + b4 * k4v.x + b5 * k5v.x + b6 * k6v.x);
    ynv.y = yv.y + hs * (b1 * k1v.y + b3 * k3v.y + b4 * k4v.y + b5 * k5v.y + b6 * k6v.y);
    ynv.z = yv.z + hs * (b1 * k1v.z + b3 * k3v.z + b4 * k4v.z + b5 * k5v.z + b6 * k6v.z);
    ynv.w = yv.w + hs * (b1 * k1v.w + b3 * k3v.w + b4 * k4v.w + b5 * k5v.w + b6 * k6v.w);
    st4(YN + gout, ynv);
    grid.sync();

    // FSAL stage k7 = f(t+hs, y_new)
    float4 k7v = run_stage(YN, 0, nullptr, nullptr, hs, TBc * (t + hs) + TCc, K7p);

    // error norm partial
    float esum = 0.f;
    {
      float errc, scv;
      errc = hs * (e1 * k1v.x + e3 * k3v.x + e4 * k4v.x + e5 * k5v.x + e6 * k6v.x + e7 * k7v.x);
      scv = ATOLc + RTOLc * fmaxf(fabsf(yv.x), fabsf(ynv.x)); errc /= scv; esum += errc * errc;
      errc = hs * (e1 * k1v.y + e3 * k3v.y + e4 * k4v.y + e5 * k5v.y + e6 * k6v.y + e7 * k7v.y);
      scv = ATOLc + RTOLc * fmaxf(fabsf(yv.y), fabsf(ynv.y)); errc /= scv; esum += errc * errc;
      errc = hs * (e1 * k1v.z + e3 * k3v.z + e4 * k4v.z + e5 * k5v.z + e6 * k6v.z + e7 * k7v.z);
      scv = ATOLc + RTOLc * fmaxf(fabsf(yv.z), fabsf(ynv.z)); errc /= scv; esum += errc * errc;
      errc = hs * (e1 * k1v.w + e3 * k3v.w + e4 * k4v.w + e5 * k5v.w + e6 * k6v.w + e7 * k7v.w);
      scv = ATOLc + RTOLc * fmaxf(fabsf(yv.w), fabsf(ynv.w)); errc /= scv; esum += errc * errc;
    }
    block_atomic_sum(esum, &ACCp[3 + it]);
    grid.sync();

    float en = sqrtf(read_acc(3 + it) / NELEMF);
    bool accept = en < 1.0f;
    float safe = fmaxf(en, 1e-10f);
    float fac = 0.9f * powf(safe, -0.2f);
    fac = accept ? fminf(10.f, fac) : fmaxf(0.2f, fac);
    if (accept) {
      t = t + hs;
      float* tmp = Y; Y = YN; YN = tmp;
      tmp = FY; FY = K7p; K7p = tmp;
    }
    h = hs * fac;
    done = done || (t >= 1.0f - 1e-7f);
    ++it;
  }

  if (blockIdx.x == 0 && threadIdx.x == 0) ACCp[32] = (Y == bufY) ? 0.f : 1.f;
}

extern "C" void kernel_launch(void* const* d_in, const int* in_sizes, int n_in,
                              void* d_out, int out_size, void* d_ws, size_t ws_size,
                              hipStream_t stream) {
  const float* x = (const float*)d_in[0];
  const float* P = (const float*)d_in[1];
  const float* C = (const float*)d_in[2];
  const float* F = (const float*)d_in[3];
  float* out = (float*)d_out;
  float* ws = (float*)d_ws;

  // A0 = x @ P  -> Y buffer  (also zeroes ACC slots)
  hipLaunchKernelGGL(gemm_k512, dim3(256), dim3(256), 0, stream, x, P, ws + BUF_OFF, ws, 0);
  // Ct = C^T (as [1024][512])
  hipLaunchKernelGGL(transpose_c, dim3(512), dim3(256), 0, stream, C, ws + CT_OFF);
  // RK45 integration (cooperative: per-stage grid syncs)
  float* wsf = ws;
  void* kargs[] = {(void*)&wsf};
  hipLaunchCooperativeKernel((void*)ode_kernel, dim3(256), dim3(256), kargs, 0, stream);
  // y = A_f @ F  (A_f buffer index read from ACC[32])
  hipLaunchKernelGGL(gemm_k512, dim3(256), dim3(256), 0, stream, (const float*)nullptr, F, out, ws, 1);
}

// Round 2
// 960.347 us; speedup vs baseline: 1.6356x; 1.6356x over previous
//
#include <hip/hip_runtime.h>
#include <hip/hip_cooperative_groups.h>
#include <cmath>

namespace cg = cooperative_groups;

typedef float floatx4 __attribute__((ext_vector_type(4)));
typedef __bf16 bf16x8 __attribute__((ext_vector_type(8)));

#define NB 512
#define NDT 512
#define NEL (NB * NDT)
#define NELF 262144.0f

// ws layout (float offsets)
#define ACC_OFF 0               // 64 scalar slots: 0,1,2 = d0/d1/d2; 3..22 = en per iter
#define BUF_OFF 64              // y buffer (NEL fp32): A0 in, A_f out
#define AFRAG_OFF (64 + NEL)    // basis A-fragments, bf16, 512x1024 (1 MiB)
#define BFRAG_OFF (64 + 2 * NEL) // packed Ct B-fragments, bf16, 1024x512 (1 MiB)

#define RTOLc 1e-3f
#define ATOLc 1e-6f
#define TAc 1.0f
#define TBc 1.0f
#define TCc 0.0f

union UB { uint4 u; bf16x8 v; };

__device__ __forceinline__ uint32_t f2bf(float f) {
  uint32_t u = __float_as_uint(f);
  return (u + 0x7fffu + ((u >> 16) & 1u)) >> 16;
}

// ---------------- fp32 GEMM for A0 = x@P and out = A_f@F (run twice, not hot) ----
__global__ __launch_bounds__(256) void gemm_k512(const float* __restrict__ A,
                                                 const float* __restrict__ Bm,
                                                 float* __restrict__ out,
                                                 float* __restrict__ zacc) {
  __shared__ float sc[16][520];
  if (zacc && blockIdx.x == 0 && threadIdx.x < 64) zacc[threadIdx.x] = 0.0f;
  int row0 = (blockIdx.x >> 3) * 16;
  int colb = (blockIdx.x & 7) * 64;
  for (int idx = threadIdx.x; idx < 16 * 512; idx += 256) {
    int r = idx >> 9, kk = idx & 511;
    sc[r][kk] = A[(size_t)(row0 + r) * NDT + kk];
  }
  __syncthreads();
  int row = threadIdx.x >> 4;
  int col0 = colb + (threadIdx.x & 15) * 4;
  float4 acc = {0.f, 0.f, 0.f, 0.f};
  const float* bp = Bm + col0;
#pragma unroll 4
  for (int kk = 0; kk < 512; kk += 4) {
    float4 sv = *(const float4*)(&sc[row][kk]);
    float4 b0 = *(const float4*)(bp + (size_t)(kk + 0) * NDT);
    float4 b1 = *(const float4*)(bp + (size_t)(kk + 1) * NDT);
    float4 b2 = *(const float4*)(bp + (size_t)(kk + 2) * NDT);
    float4 b3 = *(const float4*)(bp + (size_t)(kk + 3) * NDT);
    acc.x += sv.x * b0.x + sv.y * b1.x + sv.z * b2.x + sv.w * b3.x;
    acc.y += sv.x * b0.y + sv.y * b1.y + sv.z * b2.y + sv.w * b3.y;
    acc.z += sv.x * b0.z + sv.y * b1.z + sv.z * b2.z + sv.w * b3.z;
    acc.w += sv.x * b0.w + sv.y * b1.w + sv.z * b2.w + sv.w * b3.w;
  }
  *(float4*)(out + (size_t)(row0 + row) * NDT + col0) = acc;
}

// ---------------- pack C[i][jj][s] (fp32) -> bf16 B-fragments of Ct[K=2jj+s][i] ----
// frag id f = (i>>4)*32 + (K>>5); lane = (i&15) | (((K>>3)&3)<<4); j = K&7
__global__ __launch_bounds__(256) void pack_c(const float* __restrict__ C,
                                              __bf16* __restrict__ Bf) {
  int t = blockIdx.x * 256 + threadIdx.x;  // 0..131071
  int i = t >> 8;
  int pr = t & 255;                        // covers K0 = pr*4
  floatx4 v = *(const floatx4*)(C + (size_t)i * 1024 + pr * 4);
  uint32_t w0 = f2bf(v[0]) | (f2bf(v[1]) << 16);
  uint32_t w1 = f2bf(v[2]) | (f2bf(v[3]) << 16);
  int c0 = i >> 4;
  int kc = pr >> 3;
  int lq = (pr >> 1) & 3;
  int ln = (i & 15) | (lq << 4);
  int jp = (pr & 1) * 4;
  uint2 val; val.x = w0; val.y = w1;
  *(uint2*)(Bf + ((size_t)(c0 * 32 + kc) * 64 + ln) * 8 + jp) = val;
}

// ---------------- cooperative RK45 with MFMA stage GEMMs ----------------
__global__ __launch_bounds__(256) void ode_mfma(float* __restrict__ ws) {
  cg::grid_group grid = cg::this_grid();
  __shared__ float red[4][32][36];   // K-split partials, padded
  __shared__ float bred[4];
  __shared__ float shb;

  float* ACCp = ws + ACC_OFF;
  float* bufY = ws + BUF_OFF;
  __bf16* Af = (__bf16*)(ws + AFRAG_OFF);
  const __bf16* Bf = (const __bf16*)(ws + BFRAG_OFF);

  const int tid = threadIdx.x;
  const int lane = tid & 63;
  const int kw = tid >> 6;          // wave id = K-split index
  const int bi = blockIdx.x >> 4;   // row block (32 rows)
  const int bj = blockIdx.x & 15;   // col block (32 cols)
  const int b_loc = tid >> 3;       // 0..31 patch row
  const int c_loc = (tid & 7) << 2; // 0..28 patch col (x4)
  const int grow = bi * 32 + b_loc;
  const int gcol = bj * 32 + c_loc;
  const size_t gidx = (size_t)grow * NDT + gcol;

  // persistent B fragments: wave kw owns K-range [kw*256, kw*256+256)
  bf16x8 Breg[2][8];
#pragma unroll
  for (int nt = 0; nt < 2; ++nt) {
    const int c0 = bj * 2 + nt;
#pragma unroll
    for (int ci = 0; ci < 8; ++ci) {
      const int kc = kw * 8 + ci;
      UB u;
      u.u = *(const uint4*)(Bf + ((size_t)(c0 * 32 + kc) * 64 + lane) * 8);
      Breg[nt][ci] = u.v;
    }
  }

  const __bf16* a0base = Af + (size_t)(bi * 2 + 0) * 16384 + (size_t)kw * 4096 + lane * 8;
  const __bf16* a1base = Af + (size_t)(bi * 2 + 1) * 16384 + (size_t)kw * 4096 + lane * 8;

  auto gemm_stage = [&]() -> floatx4 {
    floatx4 a00 = {0.f, 0.f, 0.f, 0.f}, a01 = {0.f, 0.f, 0.f, 0.f};
    floatx4 a10 = {0.f, 0.f, 0.f, 0.f}, a11 = {0.f, 0.f, 0.f, 0.f};
#pragma unroll
    for (int ci = 0; ci < 8; ++ci) {
      UB ua, ub;
      ua.u = *(const uint4*)(a0base + (size_t)ci * 512);
      ub.u = *(const uint4*)(a1base + (size_t)ci * 512);
      a00 = __builtin_amdgcn_mfma_f32_16x16x32_bf16(ua.v, Breg[0][ci], a00, 0, 0, 0);
      a01 = __builtin_amdgcn_mfma_f32_16x16x32_bf16(ua.v, Breg[1][ci], a01, 0, 0, 0);
      a10 = __builtin_amdgcn_mfma_f32_16x16x32_bf16(ub.v, Breg[0][ci], a10, 0, 0, 0);
      a11 = __builtin_amdgcn_mfma_f32_16x16x32_bf16(ub.v, Breg[1][ci], a11, 0, 0, 0);
    }
    __syncthreads();  // guard red reuse
    const int q = lane >> 4, cn = lane & 15;
#pragma unroll
    for (int r = 0; r < 4; ++r) {
      red[kw][q * 4 + r][cn] = a00[r];
      red[kw][q * 4 + r][16 + cn] = a01[r];
      red[kw][16 + q * 4 + r][cn] = a10[r];
      red[kw][16 + q * 4 + r][16 + cn] = a11[r];
    }
    __syncthreads();
    floatx4 s = *(const floatx4*)&red[0][b_loc][c_loc];
    s += *(const floatx4*)&red[1][b_loc][c_loc];
    s += *(const floatx4*)&red[2][b_loc][c_loc];
    s += *(const floatx4*)&red[3][b_loc][c_loc];
    return s;
  };

  auto block_atomic_sum = [&](float v, float* dst) {
    __syncthreads();  // guard bred reuse
#pragma unroll
    for (int o = 32; o; o >>= 1) v += __shfl_down(v, o, 64);
    if ((tid & 63) == 0) bred[tid >> 6] = v;
    __syncthreads();
    if (tid == 0) atomicAdd(dst, bred[0] + bred[1] + bred[2] + bred[3]);
  };

  auto read_acc = [&](int slot) -> float {
    __syncthreads();
    if (tid == 0) shb = atomicAdd(&ACCp[slot], 0.0f);
    __syncthreads();
    return shb;
  };

  // write thread's 4 basis values (sin/cos interleaved, bf16) in A-frag layout
  auto write_basis = [&](floatx4 av, float tph) {
    uint32_t w[4];
#pragma unroll
    for (int e = 0; e < 4; ++e) {
      float s, c;
      __sincosf(TAc * av[e] + tph, &s, &c);
      w[e] = f2bf(s) | (f2bf(c) << 16);
    }
    const int K0 = gcol * 2;
    const int rt = grow >> 4, kc = K0 >> 5;
    const int ln = (grow & 15) | (((K0 >> 3) & 3) << 4);
    *(uint4*)(Af + ((size_t)(rt * 32 + kc) * 64 + ln) * 8) = make_uint4(w[0], w[1], w[2], w[3]);
  };

  floatx4 yv = *(const floatx4*)(bufY + gidx);

  // ---- initial step size (scipy _select_initial_step) ----
  write_basis(yv, TBc * 0.0f + TCc);
  grid.sync();

  floatx4 fyv = gemm_stage();  // f0
  {
    float s0 = 0.f, s1 = 0.f;
#pragma unroll
    for (int e = 0; e < 4; ++e) {
      float scv = ATOLc + RTOLc * fabsf(yv[e]);
      float a = yv[e] / scv, b = fyv[e] / scv;
      s0 += a * a;
      s1 += b * b;
    }
    block_atomic_sum(s0, &ACCp[0]);
    block_atomic_sum(s1, &ACCp[1]);
  }
  grid.sync();

  const float d0 = sqrtf(read_acc(0) / NELF);
  const float d1 = sqrtf(read_acc(1) / NELF);
  const float h0 = (d0 < 1e-5f || d1 < 1e-5f) ? 1e-6f : 0.01f * d0 / d1;
  write_basis(yv + h0 * fyv, TBc * h0 + TCc);
  grid.sync();

  floatx4 f1 = gemm_stage();  // f(t0+h0, y0+h0*f0)
  {
    float s2 = 0.f;
#pragma unroll
    for (int e = 0; e < 4; ++e) {
      float scv = ATOLc + RTOLc * fabsf(yv[e]);
      float dd = (f1[e] - fyv[e]) / scv;
      s2 += dd * dd;
    }
    block_atomic_sum(s2, &ACCp[2]);
  }
  grid.sync();

  const float d2 = sqrtf(read_acc(2) / NELF) / h0;
  const float dmax = fmaxf(d1, d2);
  const float h1i = (dmax <= 1e-15f) ? fmaxf(1e-6f, h0 * 1e-3f) : powf(0.01f / dmax, 0.2f);
  float h = fminf(fminf(100.0f * h0, h1i), 1.0f);
  float t = 0.0f;
  bool done = false;
  int it = 0;

  const float a21 = (float)(1.0 / 5.0);
  const float a31 = (float)(3.0 / 40.0), a32 = (float)(9.0 / 40.0);
  const float a41 = (float)(44.0 / 45.0), a42 = (float)(-56.0 / 15.0), a43 = (float)(32.0 / 9.0);
  const float a51 = (float)(19372.0 / 6561.0), a52 = (float)(-25360.0 / 2187.0),
              a53 = (float)(64448.0 / 6561.0), a54 = (float)(-212.0 / 729.0);
  const float a61 = (float)(9017.0 / 3168.0), a62 = (float)(-355.0 / 33.0),
              a63 = (float)(46732.0 / 5247.0), a64 = (float)(49.0 / 176.0),
              a65 = (float)(-5103.0 / 18656.0);
  const float b1 = (float)(35.0 / 384.0), b3 = (float)(500.0 / 1113.0), b4 = (float)(125.0 / 192.0),
              b5 = (float)(-2187.0 / 6784.0), b6 = (float)(11.0 / 84.0);
  const float e1c = (float)(71.0 / 57600.0), e3c = (float)(-71.0 / 16695.0),
              e4c = (float)(71.0 / 1920.0), e5c = (float)(-17253.0 / 339200.0),
              e6c = (float)(22.0 / 525.0), e7c = (float)(-1.0 / 40.0);
  const float c89 = (float)(8.0 / 9.0);

  float hs = fminf(h, 1.0f - t);
  write_basis(yv + (hs * a21) * fyv, TBc * (t + 0.2f * hs) + TCc);
  grid.sync();

  while (true) {
    floatx4 k2 = gemm_stage();
    write_basis(yv + hs * (a31 * fyv + a32 * k2), TBc * (t + 0.3f * hs) + TCc);
    grid.sync();

    floatx4 k3 = gemm_stage();
    write_basis(yv + hs * (a41 * fyv + a42 * k2 + a43 * k3), TBc * (t + 0.8f * hs) + TCc);
    grid.sync();

    floatx4 k4 = gemm_stage();
    write_basis(yv + hs * (a51 * fyv + a52 * k2 + a53 * k3 + a54 * k4),
                TBc * (t + c89 * hs) + TCc);
    grid.sync();

    floatx4 k5 = gemm_stage();
    write_basis(yv + hs * (a61 * fyv + a62 * k2 + a63 * k3 + a64 * k4 + a65 * k5),
                TBc * (t + hs) + TCc);
    grid.sync();

    floatx4 k6 = gemm_stage();
    floatx4 ynv = yv + hs * (b1 * fyv + b3 * k3 + b4 * k4 + b5 * k5 + b6 * k6);
    write_basis(ynv, TBc * (t + hs) + TCc);  // FSAL stage input
    grid.sync();

    floatx4 k7 = gemm_stage();
    {
      floatx4 errv = hs * (e1c * fyv + e3c * k3 + e4c * k4 + e5c * k5 + e6c * k6 + e7c * k7);
      float es = 0.f;
#pragma unroll
      for (int e = 0; e < 4; ++e) {
        float scv = ATOLc + RTOLc * fmaxf(fabsf(yv[e]), fabsf(ynv[e]));
        float dd = errv[e] / scv;
        es += dd * dd;
      }
      block_atomic_sum(es, &ACCp[3 + it]);
    }
    grid.sync();

    const float en = sqrtf(read_acc(3 + it) / NELF);
    const bool accept = en < 1.0f;
    const float safe = fmaxf(en, 1e-10f);
    float fac = 0.9f * powf(safe, -0.2f);
    fac = accept ? fminf(10.0f, fac) : fmaxf(0.2f, fac);
    if (accept) {
      t = t + hs;
      yv = ynv;
      fyv = k7;
    }
    h = hs * fac;
    done = done || (t >= 1.0f - 1e-7f);
    ++it;
    if (done || it >= 20) break;
    hs = fminf(h, 1.0f - t);
    write_basis(yv + (hs * a21) * fyv, TBc * (t + 0.2f * hs) + TCc);
    grid.sync();
  }

  *(floatx4*)(bufY + gidx) = yv;  // A_f for the output GEMM
}

extern "C" void kernel_launch(void* const* d_in, const int* in_sizes, int n_in,
                              void* d_out, int out_size, void* d_ws, size_t ws_size,
                              hipStream_t stream) {
  const float* x = (const float*)d_in[0];
  const float* P = (const float*)d_in[1];
  const float* C = (const float*)d_in[2];
  const float* F = (const float*)d_in[3];
  float* out = (float*)d_out;
  float* ws = (float*)d_ws;

  // A0 = x @ P -> bufY (also zeroes ACC slots)
  hipLaunchKernelGGL(gemm_k512, dim3(256), dim3(256), 0, stream, x, P, ws + BUF_OFF, ws);
  // pack Ct into bf16 B-fragments (once)
  hipLaunchKernelGGL(pack_c, dim3(512), dim3(256), 0, stream, C, (__bf16*)(ws + BFRAG_OFF));
  // cooperative RK45 integration
  float* wsf = ws;
  void* kargs[] = {(void*)&wsf};
  hipLaunchCooperativeKernel((void*)ode_mfma, dim3(256), dim3(256), kargs, 0, stream);
  // out = A_f @ F
  hipLaunchKernelGGL(gemm_k512, dim3(256), dim3(256), 0, stream, ws + BUF_OFF, F, out,
                     (float*)nullptr);
}

// Round 3
// 621.885 us; speedup vs baseline: 2.5258x; 1.5443x over previous
//
#include <hip/hip_runtime.h>
#include <cmath>

typedef float floatx4 __attribute__((ext_vector_type(4)));
typedef __bf16 bf16x8 __attribute__((ext_vector_type(8)));

#define NDT 512
#define NEL (512 * 512)
#define NELF 262144.0f
#define BUF_OFF 64
#define BFRAG_OFF (64 + NEL)
#define GBLOCKS 32

#define RTOLc 1e-3f
#define ATOLc 1e-6f
#define TAc 1.0f
#define TBc 1.0f
#define TCc 0.0f

union UB { uint4 u; bf16x8 v; };

__device__ __forceinline__ uint32_t f2bf(float f) {
  uint32_t u = __float_as_uint(f);
  return (u + 0x7fffu + ((u >> 16) & 1u)) >> 16;
}

// ---------------- fp32 GEMM for A0 = x@P and out = A_f@F (runs twice, not hot) ----
__global__ __launch_bounds__(256) void gemm_k512(const float* __restrict__ A,
                                                 const float* __restrict__ Bm,
                                                 float* __restrict__ out,
                                                 float* __restrict__ zacc) {
  __shared__ float sc[16][520];
  if (zacc && blockIdx.x == 0 && threadIdx.x < 64) zacc[threadIdx.x] = 0.0f;
  int row0 = (blockIdx.x >> 3) * 16;
  int colb = (blockIdx.x & 7) * 64;
  for (int idx = threadIdx.x; idx < 16 * 512; idx += 256) {
    int r = idx >> 9, kk = idx & 511;
    sc[r][kk] = A[(size_t)(row0 + r) * NDT + kk];
  }
  __syncthreads();
  int row = threadIdx.x >> 4;
  int col0 = colb + (threadIdx.x & 15) * 4;
  float4 acc = {0.f, 0.f, 0.f, 0.f};
  const float* bp = Bm + col0;
#pragma unroll 4
  for (int kk = 0; kk < 512; kk += 4) {
    float4 sv = *(const float4*)(&sc[row][kk]);
    float4 b0 = *(const float4*)(bp + (size_t)(kk + 0) * NDT);
    float4 b1 = *(const float4*)(bp + (size_t)(kk + 1) * NDT);
    float4 b2 = *(const float4*)(bp + (size_t)(kk + 2) * NDT);
    float4 b3 = *(const float4*)(bp + (size_t)(kk + 3) * NDT);
    acc.x += sv.x * b0.x + sv.y * b1.x + sv.z * b2.x + sv.w * b3.x;
    acc.y += sv.x * b0.y + sv.y * b1.y + sv.z * b2.y + sv.w * b3.y;
    acc.z += sv.x * b0.z + sv.y * b1.z + sv.z * b2.z + sv.w * b3.z;
    acc.w += sv.x * b0.w + sv.y * b1.w + sv.z * b2.w + sv.w * b3.w;
  }
  *(float4*)(out + (size_t)(row0 + row) * NDT + col0) = acc;
}

// ---------------- pack C (fp32 [512][512][2]) -> bf16 B-fragments of Ct[K][i] ----
__global__ __launch_bounds__(256) void pack_c(const float* __restrict__ C,
                                              __bf16* __restrict__ Bf) {
  int t = blockIdx.x * 256 + threadIdx.x;  // 0..131071
  int i = t >> 8;
  int pr = t & 255;  // K0 = pr*4
  floatx4 v = *(const floatx4*)(C + (size_t)i * 1024 + pr * 4);
  uint32_t w0 = f2bf(v[0]) | (f2bf(v[1]) << 16);
  uint32_t w1 = f2bf(v[2]) | (f2bf(v[3]) << 16);
  int c0 = i >> 4;
  int kc = pr >> 3;
  int lq = (pr >> 1) & 3;
  int ln = (i & 15) | (lq << 4);
  int jp = (pr & 1) * 4;
  uint2 val; val.x = w0; val.y = w1;
  *(uint2*)(Bf + ((size_t)(c0 * 32 + kc) * 64 + ln) * 8 + jp) = val;
}

// ---------------- cooperative RK45: block owns 16 rows end-to-end ----------------
__global__ __launch_bounds__(512, 2) void ode_mfma(float* __restrict__ ws) {
  __shared__ __align__(16) unsigned char ldsA[32 * 1152];  // A-frags, skewed
  __shared__ float bred[8];
  __shared__ float shb0, shb1;

  float* ACC = ws;                        // [0..31] fp32 sums
  unsigned* CNT = ((unsigned*)ws) + 32;   // [0..31] arrival counters
  float* bufY = ws + BUF_OFF;
  const __bf16* Bf = (const __bf16*)(ws + BFRAG_OFF);

  const int tid = threadIdx.x;
  const int lane = tid & 63;
  const int w = tid >> 6;      // wave id: cols 64w..64w+63
  const int q = lane >> 4;     // row quad
  const int cn = lane & 15;
  const int g = cn >> 2;
  const int bi = blockIdx.x;   // rows 16bi..16bi+15

  // LDS A-frag addressing: line (kc, al) at kc*1152 + al*16 + (al>>4)*32
  const int wbase = (4 * w) * 1152 + (4 * q + 16 * g) * 16 + g * 32 + (cn & 3) * 4;
  const int rbase = lane * 16 + (lane >> 4) * 32;
  const __bf16* Blane = Bf + (size_t)lane * 8;

  floatx4 y[4], fy[4], k2[4], k3[4], k4[4], k5[4], k6[4], k7[4], yn[4], av[4];

  auto write_basis = [&](const floatx4* a, float targ) {
#pragma unroll
    for (int f = 0; f < 4; ++f) {
#pragma unroll
      for (int ri = 0; ri < 4; ++ri) {
        float s, c;
        __sincosf(TAc * a[f][ri] + targ, &s, &c);
        *(uint32_t*)(ldsA + wbase + f * 1152 + ri * 16) = f2bf(s) | (f2bf(c) << 16);
      }
    }
  };

  auto gemm = [&](floatx4* out) {
    __syncthreads();  // basis writes visible to all waves
    floatx4 acc0 = {0.f, 0.f, 0.f, 0.f}, acc1 = acc0, acc2 = acc0, acc3 = acc0;
#pragma unroll
    for (int kc = 0; kc < 32; ++kc) {
      UB a;
      a.u = *(const uint4*)(ldsA + kc * 1152 + rbase);
      UB b0, b1, b2, b3;
      b0.u = *(const uint4*)(Blane + ((size_t)(4 * w + 0) * 32 + kc) * 512);
      b1.u = *(const uint4*)(Blane + ((size_t)(4 * w + 1) * 32 + kc) * 512);
      b2.u = *(const uint4*)(Blane + ((size_t)(4 * w + 2) * 32 + kc) * 512);
      b3.u = *(const uint4*)(Blane + ((size_t)(4 * w + 3) * 32 + kc) * 512);
      acc0 = __builtin_amdgcn_mfma_f32_16x16x32_bf16(a.v, b0.v, acc0, 0, 0, 0);
      acc1 = __builtin_amdgcn_mfma_f32_16x16x32_bf16(a.v, b1.v, acc1, 0, 0, 0);
      acc2 = __builtin_amdgcn_mfma_f32_16x16x32_bf16(a.v, b2.v, acc2, 0, 0, 0);
      acc3 = __builtin_amdgcn_mfma_f32_16x16x32_bf16(a.v, b3.v, acc3, 0, 0, 0);
    }
    out[0] = acc0; out[1] = acc1; out[2] = acc2; out[3] = acc3;
    __syncthreads();  // all reads done before next basis overwrite
  };

  auto block_sum = [&](float v) -> float {
#pragma unroll
    for (int o = 32; o; o >>= 1) v += __shfl_down(v, o, 64);
    __syncthreads();
    if (lane == 0) bred[w] = v;
    __syncthreads();
    float r = 0.f;
    if (tid == 0) {
#pragma unroll
      for (int i = 0; i < 8; ++i) r += bred[i];
    }
    return r;
  };

  auto grid_reduce1 = [&](float v, int s) -> float {
    float b = block_sum(v);
    if (tid == 0) {
      atomicAdd(&ACC[s], b);
      __threadfence();
      atomicAdd(&CNT[s], 1u);
      while (__hip_atomic_load(&CNT[s], __ATOMIC_ACQUIRE, __HIP_MEMORY_SCOPE_AGENT) <
             (unsigned)GBLOCKS)
        __builtin_amdgcn_s_sleep(2);
      shb0 = __hip_atomic_load(&ACC[s], __ATOMIC_RELAXED, __HIP_MEMORY_SCOPE_AGENT);
    }
    __syncthreads();
    return shb0;
  };

  auto grid_reduce2 = [&](float va, float vb, int sa, int sb) -> float2 {
    float ba = block_sum(va);
    float bb = block_sum(vb);
    if (tid == 0) {
      atomicAdd(&ACC[sa], ba);
      atomicAdd(&ACC[sb], bb);
      __threadfence();
      atomicAdd(&CNT[sa], 1u);
      while (__hip_atomic_load(&CNT[sa], __ATOMIC_ACQUIRE, __HIP_MEMORY_SCOPE_AGENT) <
             (unsigned)GBLOCKS)
        __builtin_amdgcn_s_sleep(2);
      shb0 = __hip_atomic_load(&ACC[sa], __ATOMIC_RELAXED, __HIP_MEMORY_SCOPE_AGENT);
      shb1 = __hip_atomic_load(&ACC[sb], __ATOMIC_RELAXED, __HIP_MEMORY_SCOPE_AGENT);
    }
    __syncthreads();
    return make_float2(shb0, shb1);
  };

  // load initial state y0 = A0 (C-layout ownership)
#pragma unroll
  for (int f = 0; f < 4; ++f) {
    const int c = 64 * w + 16 * f + cn;
#pragma unroll
    for (int ri = 0; ri < 4; ++ri)
      y[f][ri] = bufY[(size_t)(16 * bi + 4 * q + ri) * NDT + c];
  }

  // ---- initial step selection (scipy _select_initial_step) ----
  write_basis(y, TCc + TBc * 0.0f);
  gemm(fy);  // f0
  {
    float s0 = 0.f, s1 = 0.f;
#pragma unroll
    for (int f = 0; f < 4; ++f)
#pragma unroll
      for (int ri = 0; ri < 4; ++ri) {
        float sv = ATOLc + RTOLc * fabsf(y[f][ri]);
        float a = y[f][ri] / sv, b = fy[f][ri] / sv;
        s0 += a * a;
        s1 += b * b;
      }
    float2 d01 = grid_reduce2(s0, s1, 0, 1);
    const float d0 = sqrtf(d01.x / NELF);
    const float d1 = sqrtf(d01.y / NELF);
    const float h0 = (d0 < 1e-5f || d1 < 1e-5f) ? 1e-6f : 0.01f * d0 / d1;
#pragma unroll
    for (int f = 0; f < 4; ++f) av[f] = y[f] + h0 * fy[f];
    write_basis(av, TCc + TBc * h0);
    gemm(k2);  // f1 (temp)
    float s2 = 0.f;
#pragma unroll
    for (int f = 0; f < 4; ++f)
#pragma unroll
      for (int ri = 0; ri < 4; ++ri) {
        float sv = ATOLc + RTOLc * fabsf(y[f][ri]);
        float dd = (k2[f][ri] - fy[f][ri]) / sv;
        s2 += dd * dd;
      }
    const float d2 = sqrtf(grid_reduce1(s2, 2) / NELF) / h0;
    const float dmax = fmaxf(d1, d2);
    const float h1i = (dmax <= 1e-15f) ? fmaxf(1e-6f, h0 * 1e-3f) : powf(0.01f / dmax, 0.2f);
    shb0 = 0.f;  // reuse barrier var safely below
    __syncthreads();
    // h via register (uniform): continue below
    float h = fminf(fminf(100.0f * h0, h1i), 1.0f);
    float t = 0.0f;
    bool done = false;
    int it = 0;

    const float a21 = (float)(1.0 / 5.0);
    const float a31 = (float)(3.0 / 40.0), a32 = (float)(9.0 / 40.0);
    const float a41 = (float)(44.0 / 45.0), a42 = (float)(-56.0 / 15.0), a43 = (float)(32.0 / 9.0);
    const float a51 = (float)(19372.0 / 6561.0), a52 = (float)(-25360.0 / 2187.0),
                a53 = (float)(64448.0 / 6561.0), a54 = (float)(-212.0 / 729.0);
    const float a61 = (float)(9017.0 / 3168.0), a62 = (float)(-355.0 / 33.0),
                a63 = (float)(46732.0 / 5247.0), a64 = (float)(49.0 / 176.0),
                a65 = (float)(-5103.0 / 18656.0);
    const float b1 = (float)(35.0 / 384.0), b3 = (float)(500.0 / 1113.0),
                b4 = (float)(125.0 / 192.0), b5 = (float)(-2187.0 / 6784.0),
                b6 = (float)(11.0 / 84.0);
    const float e1c = (float)(71.0 / 57600.0), e3c = (float)(-71.0 / 16695.0),
                e4c = (float)(71.0 / 1920.0), e5c = (float)(-17253.0 / 339200.0),
                e6c = (float)(22.0 / 525.0), e7c = (float)(-1.0 / 40.0);
    const float c89 = (float)(8.0 / 9.0);

    while (true) {
      const float hs = fminf(h, 1.0f - t);

#pragma unroll
      for (int f = 0; f < 4; ++f) av[f] = y[f] + (hs * a21) * fy[f];
      write_basis(av, TCc + TBc * (t + 0.2f * hs));
      gemm(k2);

#pragma unroll
      for (int f = 0; f < 4; ++f) av[f] = y[f] + hs * (a31 * fy[f] + a32 * k2[f]);
      write_basis(av, TCc + TBc * (t + 0.3f * hs));
      gemm(k3);

#pragma unroll
      for (int f = 0; f < 4; ++f)
        av[f] = y[f] + hs * (a41 * fy[f] + a42 * k2[f] + a43 * k3[f]);
      write_basis(av, TCc + TBc * (t + 0.8f * hs));
      gemm(k4);

#pragma unroll
      for (int f = 0; f < 4; ++f)
        av[f] = y[f] + hs * (a51 * fy[f] + a52 * k2[f] + a53 * k3[f] + a54 * k4[f]);
      write_basis(av, TCc + TBc * (t + c89 * hs));
      gemm(k5);

#pragma unroll
      for (int f = 0; f < 4; ++f)
        av[f] = y[f] + hs * (a61 * fy[f] + a62 * k2[f] + a63 * k3[f] + a64 * k4[f] + a65 * k5[f]);
      write_basis(av, TCc + TBc * (t + hs));
      gemm(k6);

#pragma unroll
      for (int f = 0; f < 4; ++f)
        yn[f] = y[f] + hs * (b1 * fy[f] + b3 * k3[f] + b4 * k4[f] + b5 * k5[f] + b6 * k6[f]);
      write_basis(yn, TCc + TBc * (t + hs));
      gemm(k7);  // FSAL

      float es = 0.f;
#pragma unroll
      for (int f = 0; f < 4; ++f)
#pragma unroll
        for (int ri = 0; ri < 4; ++ri) {
          float errc = hs * (e1c * fy[f][ri] + e3c * k3[f][ri] + e4c * k4[f][ri] +
                             e5c * k5[f][ri] + e6c * k6[f][ri] + e7c * k7[f][ri]);
          float sv = ATOLc + RTOLc * fmaxf(fabsf(y[f][ri]), fabsf(yn[f][ri]));
          float dd = errc / sv;
          es += dd * dd;
        }
      const float en = sqrtf(grid_reduce1(es, 3 + it) / NELF);
      const bool accept = en < 1.0f;
      const float safe = fmaxf(en, 1e-10f);
      float fac = 0.9f * powf(safe, -0.2f);
      fac = accept ? fminf(10.0f, fac) : fmaxf(0.2f, fac);
      if (accept) {
        t = t + hs;
#pragma unroll
        for (int f = 0; f < 4; ++f) { y[f] = yn[f]; fy[f] = k7[f]; }
      }
      h = hs * fac;
      done = done || (t >= 1.0f - 1e-7f);
      ++it;
      if (done || it >= 20) break;
    }
  }

  // store A_f for the output GEMM
#pragma unroll
  for (int f = 0; f < 4; ++f) {
    const int c = 64 * w + 16 * f + cn;
#pragma unroll
    for (int ri = 0; ri < 4; ++ri)
      bufY[(size_t)(16 * bi + 4 * q + ri) * NDT + c] = y[f][ri];
  }
}

extern "C" void kernel_launch(void* const* d_in, const int* in_sizes, int n_in,
                              void* d_out, int out_size, void* d_ws, size_t ws_size,
                              hipStream_t stream) {
  (void)in_sizes; (void)n_in; (void)out_size; (void)ws_size;
  const float* x = (const float*)d_in[0];
  const float* P = (const float*)d_in[1];
  const float* C = (const float*)d_in[2];
  const float* F = (const float*)d_in[3];
  float* out = (float*)d_out;
  float* ws = (float*)d_ws;

  // A0 = x @ P -> bufY (also zeroes the 64 ACC/CNT slots)
  hipLaunchKernelGGL(gemm_k512, dim3(256), dim3(256), 0, stream, x, P, ws + BUF_OFF, ws);
  // pack Ct into bf16 B-fragments (once)
  hipLaunchKernelGGL(pack_c, dim3(512), dim3(256), 0, stream, C, (__bf16*)(ws + BFRAG_OFF));
  // cooperative RK45 (custom atomic reductions; co-residency guaranteed)
  float* wsf = ws;
  void* kargs[] = {(void*)&wsf};
  hipLaunchCooperativeKernel((void*)ode_mfma, dim3(GBLOCKS), dim3(512), kargs, 0, stream);
  // out = A_f @ F
  hipLaunchKernelGGL(gemm_k512, dim3(256), dim3(256), 0, stream, ws + BUF_OFF, F, out,
                     (float*)nullptr);
}